// Round 1
// baseline (203.360 us; speedup 1.0000x reference)
//
#include <hip/hip_runtime.h>
#include <math.h>

#define N_BINS 15

// One wave (64 lanes) per row. C=1000 floats = 250 float4; each lane loads 4
// float4 (indices lane, lane+64, lane+128, lane+192; last round masked) and
// keeps them in registers so the max-pass and sum-exp pass touch HBM once.
__global__ __launch_bounds__(256) void ece_main(const float* __restrict__ logits,
                                                const int* __restrict__ labels,
                                                float* __restrict__ gbins, // [3][N_BINS]
                                                int N, int C) {
    __shared__ float sb[3 * N_BINS];
    const int tid = threadIdx.x;
    if (tid < 3 * N_BINS) sb[tid] = 0.0f;
    __syncthreads();

    const int lane = tid & 63;
    const int wid  = tid >> 6;
    const int wavesTotal = gridDim.x * (blockDim.x >> 6);
    const int C4 = C >> 2;  // 250 for C=1000

    for (int row = blockIdx.x * (blockDim.x >> 6) + wid; row < N; row += wavesTotal) {
        const float4* rp = (const float4*)(logits + (size_t)row * C);
        float4 v[4];
        #pragma unroll
        for (int c = 0; c < 4; ++c) {
            int f4i = c * 64 + lane;
            if (f4i < C4) {
                v[c] = rp[f4i];
            } else {
                v[c] = make_float4(-INFINITY, -INFINITY, -INFINITY, -INFINITY);
            }
        }

        // per-lane max + first-occurrence argmax (ascending scan, strict >)
        float m = -INFINITY;
        int   mi = 0x7fffffff;
        #pragma unroll
        for (int c = 0; c < 4; ++c) {
            const float* e = (const float*)&v[c];
            int base = (c * 64 + lane) * 4;
            #pragma unroll
            for (int j = 0; j < 4; ++j) {
                if (e[j] > m) { m = e[j]; mi = base + j; }
            }
        }
        // wave reduce: max, tie-break to smallest index
        #pragma unroll
        for (int off = 1; off < 64; off <<= 1) {
            float om = __shfl_xor(m, off, 64);
            int   oi = __shfl_xor(mi, off, 64);
            if (om > m || (om == m && oi < mi)) { m = om; mi = oi; }
        }

        // sum of exp(x - max); masked lanes contribute exp(-inf)=0
        float s = 0.0f;
        #pragma unroll
        for (int c = 0; c < 4; ++c) {
            const float* e = (const float*)&v[c];
            #pragma unroll
            for (int j = 0; j < 4; ++j) s += __expf(e[j] - m);
        }
        #pragma unroll
        for (int off = 1; off < 64; off <<= 1) s += __shfl_xor(s, off, 64);

        if (lane == 0) {
            float conf = 1.0f / s;                        // exp(max-max)/Z = 1/Z
            int bin = (int)ceilf(conf * (float)N_BINS) - 1;
            bin = bin < 0 ? 0 : (bin > N_BINS - 1 ? N_BINS - 1 : bin);
            float acc = (mi == labels[row]) ? 1.0f : 0.0f;
            atomicAdd(&sb[bin], 1.0f);
            atomicAdd(&sb[N_BINS + bin], conf);
            atomicAdd(&sb[2 * N_BINS + bin], acc);
        }
    }
    __syncthreads();
    if (tid < 3 * N_BINS) atomicAdd(&gbins[tid], sb[tid]);
}

// Epilogue: 31 outputs = [ece, confs_binned[15], accs_binned[15]]
__global__ void ece_final(const float* __restrict__ gbins, float* __restrict__ out,
                          float invN) {
    __shared__ float s_ece[N_BINS];
    int i = threadIdx.x;
    if (i < N_BINS) {
        float cnt   = gbins[i];
        float sconf = gbins[N_BINS + i];
        float sacc  = gbins[2 * N_BINS + i];
        bool  ne    = cnt > 0.0f;
        float sc    = ne ? cnt : 1.0f;
        float avg_conf = sconf / sc;
        float avg_acc  = sacc / sc;
        float prop     = cnt * invN;
        s_ece[i] = ne ? fabsf(avg_conf - avg_acc) * prop : 0.0f;
        out[1 + i]          = ne ? avg_conf : ((float)i + 0.5f) / (float)N_BINS;
        out[1 + N_BINS + i] = ne ? avg_acc  : 0.0f;
    }
    __syncthreads();
    if (i == 0) {
        float e = 0.0f;
        for (int j = 0; j < N_BINS; ++j) e += s_ece[j];
        out[0] = e;
    }
}

extern "C" void kernel_launch(void* const* d_in, const int* in_sizes, int n_in,
                              void* d_out, int out_size, void* d_ws, size_t ws_size,
                              hipStream_t stream) {
    const float* logits = (const float*)d_in[0];
    const int*   labels = (const int*)d_in[1];
    int N = in_sizes[1];
    int C = in_sizes[0] / N;   // 1000

    float* gbins = (float*)d_ws;  // [3][N_BINS] accumulators
    hipMemsetAsync(gbins, 0, 3 * N_BINS * sizeof(float), stream);

    const int blocks = 2048;  // 8192 waves, 32 rows/wave grid-stride
    ece_main<<<blocks, 256, 0, stream>>>(logits, labels, gbins, N, C);
    ece_final<<<1, 64, 0, stream>>>(gbins, (float*)d_out, 1.0f / (float)N);
}

// Round 2
// 203.205 us; speedup vs baseline: 1.0008x; 1.0008x over previous
//
#include <hip/hip_runtime.h>
#include <math.h>

#define N_BINS 15

// One wave (64 lanes) per row, grid-stride over rows, software-prefetched:
// row r+1's 4 float4 loads are issued before row r's reduction, so each wave
// keeps the memory pipe busy during the shuffle/exp phase.
__global__ __launch_bounds__(256) void ece_main(const float* __restrict__ logits,
                                                const int* __restrict__ labels,
                                                float* __restrict__ gbins, // [3][N_BINS]
                                                int N, int C) {
    __shared__ float sb[3 * N_BINS];
    const int tid = threadIdx.x;
    if (tid < 3 * N_BINS) sb[tid] = 0.0f;
    __syncthreads();

    const int lane = tid & 63;
    const int wid  = tid >> 6;
    const int wavesPerBlock = blockDim.x >> 6;
    const int wavesTotal = gridDim.x * wavesPerBlock;
    const int C4 = C >> 2;  // 250 for C=1000

    int row = blockIdx.x * wavesPerBlock + wid;

    float4 v[4];
    if (row < N) {
        const float4* rp = (const float4*)(logits + (size_t)row * C);
        #pragma unroll
        for (int c = 0; c < 4; ++c) {
            int f4i = c * 64 + lane;
            v[c] = (f4i < C4) ? rp[f4i]
                              : make_float4(-INFINITY, -INFINITY, -INFINITY, -INFINITY);
        }
    }

    for (; row < N; row += wavesTotal) {
        // label for current row (same addr all lanes -> one 4B fetch, broadcast)
        int lbl = labels[row];

        // prefetch next row while we reduce this one
        int nrow = row + wavesTotal;
        float4 vn[4];
        if (nrow < N) {
            const float4* np = (const float4*)(logits + (size_t)nrow * C);
            #pragma unroll
            for (int c = 0; c < 4; ++c) {
                int f4i = c * 64 + lane;
                vn[c] = (f4i < C4) ? np[f4i]
                                   : make_float4(-INFINITY, -INFINITY, -INFINITY, -INFINITY);
            }
        }

        // per-lane max + first-occurrence argmax (ascending scan, strict >)
        float m = -INFINITY;
        int   mi = 0x7fffffff;
        #pragma unroll
        for (int c = 0; c < 4; ++c) {
            const float* e = (const float*)&v[c];
            int base = (c * 64 + lane) * 4;
            #pragma unroll
            for (int j = 0; j < 4; ++j) {
                if (e[j] > m) { m = e[j]; mi = base + j; }
            }
        }
        // wave reduce: max, tie-break to smallest index
        #pragma unroll
        for (int off = 1; off < 64; off <<= 1) {
            float om = __shfl_xor(m, off, 64);
            int   oi = __shfl_xor(mi, off, 64);
            if (om > m || (om == m && oi < mi)) { m = om; mi = oi; }
        }

        // sum of exp(x - max); -inf fill lanes contribute exp(-inf)=0
        float s = 0.0f;
        #pragma unroll
        for (int c = 0; c < 4; ++c) {
            const float* e = (const float*)&v[c];
            #pragma unroll
            for (int j = 0; j < 4; ++j) s += __expf(e[j] - m);
        }
        #pragma unroll
        for (int off = 1; off < 64; off <<= 1) s += __shfl_xor(s, off, 64);

        if (lane == 0) {
            float conf = 1.0f / s;                        // exp(max-max)/Z = 1/Z
            int bin = (int)ceilf(conf * (float)N_BINS) - 1;
            bin = bin < 0 ? 0 : (bin > N_BINS - 1 ? N_BINS - 1 : bin);
            float acc = (mi == lbl) ? 1.0f : 0.0f;
            atomicAdd(&sb[bin], 1.0f);
            atomicAdd(&sb[N_BINS + bin], conf);
            atomicAdd(&sb[2 * N_BINS + bin], acc);
        }

        #pragma unroll
        for (int c = 0; c < 4; ++c) v[c] = vn[c];
    }
    __syncthreads();
    if (tid < 3 * N_BINS) atomicAdd(&gbins[tid], sb[tid]);
}

// Epilogue: 31 outputs = [ece, confs_binned[15], accs_binned[15]]
__global__ void ece_final(const float* __restrict__ gbins, float* __restrict__ out,
                          float invN) {
    __shared__ float s_ece[N_BINS];
    int i = threadIdx.x;
    if (i < N_BINS) {
        float cnt   = gbins[i];
        float sconf = gbins[N_BINS + i];
        float sacc  = gbins[2 * N_BINS + i];
        bool  ne    = cnt > 0.0f;
        float sc    = ne ? cnt : 1.0f;
        float avg_conf = sconf / sc;
        float avg_acc  = sacc / sc;
        float prop     = cnt * invN;
        s_ece[i] = ne ? fabsf(avg_conf - avg_acc) * prop : 0.0f;
        out[1 + i]          = ne ? avg_conf : ((float)i + 0.5f) / (float)N_BINS;
        out[1 + N_BINS + i] = ne ? avg_acc  : 0.0f;
    }
    __syncthreads();
    if (i == 0) {
        float e = 0.0f;
        for (int j = 0; j < N_BINS; ++j) e += s_ece[j];
        out[0] = e;
    }
}

extern "C" void kernel_launch(void* const* d_in, const int* in_sizes, int n_in,
                              void* d_out, int out_size, void* d_ws, size_t ws_size,
                              hipStream_t stream) {
    const float* logits = (const float*)d_in[0];
    const int*   labels = (const int*)d_in[1];
    int N = in_sizes[1];
    int C = in_sizes[0] / N;   // 1000

    float* gbins = (float*)d_ws;  // [3][N_BINS] accumulators
    hipMemsetAsync(gbins, 0, 3 * N_BINS * sizeof(float), stream);

    const int blocks = 2048;  // 8192 waves, 32 rows/wave grid-stride
    ece_main<<<blocks, 256, 0, stream>>>(logits, labels, gbins, N, C);
    ece_final<<<1, 64, 0, stream>>>(gbins, (float*)d_out, 1.0f / (float)N);
}